// Round 13
// baseline (225.358 us; speedup 1.0000x reference)
//
#include <hip/hip_runtime.h>
#include <hip/hip_bf16.h>
#include <hip/hip_fp16.h>

// 2D DCT-II via LEVEL-2 folded f16 MFMA GEMMs.
// Per 2048-DCT: k odd -> DCT4-1024 on w (K=1024); k=4s -> DCT2-512 on u+
// (K=512); k=4s+2 -> DCT4-512 on u- (K=512). MACs = 0.75x of level-1.
// R13 change (GEMM only): 256x256/8-wave/2-barrier -> m97-proven 128x128,
// 4 waves (256 thr), BK=32, SINGLE-buffer LDS (16KB), two __syncthreads per
// K-tile. Guide's measured tile table: at this structure 128^2=912 TF vs
// 256^2=792 (our R4 measured 781). Low VGPR (~130) -> 3-4 blocks/CU, so the
// barrier drain hides under co-resident blocks (m114). Swizzle retained
// (0 conflicts R2-R12). cvt/gen unchanged from R11.

typedef _Float16 half8 __attribute__((ext_vector_type(8)));
typedef float f32x4 __attribute__((ext_vector_type(4)));
typedef unsigned int uint32;

__device__ __forceinline__ unsigned short f2h_bits(float f) {
  _Float16 h = (_Float16)f;
  return __builtin_bit_cast(unsigned short, h);
}
__device__ __forceinline__ uint32 pk2(float a, float b) {
  return f2h_bits(a) | ((uint32)f2h_bits(b) << 16);
}

__device__ __forceinline__ void gload_lds16(const unsigned short* g, unsigned short* l) {
  __builtin_amdgcn_global_load_lds((const __attribute__((address_space(1))) void*)g,
                                   (__attribute__((address_space(3))) void*)l,
                                   16, 0, 0);
}

// Stored f16 index for logical (tile row r, 16B k-slot byte cb); stored rows
// are 128B (two logical rows); slot' = ((r&1)<<2 | cb>>4) ^ ((r>>1)&7).
// Measured 0 bank conflicts (R2-R12).
__device__ __forceinline__ int swz_idx(int r, int cbyte) {
  int b = (r >> 1) * 128 + ((((r & 1) << 6) | cbyte) ^ (((r >> 1) & 7) << 4));
  return b >> 1;
}

// Stage a 128x32 f16 tile from G (row-major, stride ld) with 256 threads;
// LDS dest LINEAR, swizzle realized by inverse-permuted global source.
__device__ __forceinline__ void stage_tile128(const unsigned short* __restrict__ G,
                                              int rowbase, int k0, int ld,
                                              unsigned short* lds, int wave, int lane) {
#pragma unroll
  for (int c = 0; c < 2; ++c) {
    const int p = c * 32 + wave * 8 + (lane >> 3);   // stored 128B row [0,64)
    const int v = (lane & 7) ^ ((lane >> 3) & 7);    // inverse slot swizzle
    const int r = 2 * p + (v >> 2);                  // logical tile row [0,128)
    const int kslot = v & 3;
    gload_lds16(G + (size_t)(rowbase + r) * ld + (k0 + kslot * 8),
                lds + (c * 32 + wave * 8) * 64);     // wave-uniform dest
  }
}

// ---- convert + FULL 2-level 2D fold, LDS-bounce (R11, unchanged) ------------
__global__ __launch_bounds__(256) void cvt_fold22(const float* __restrict__ x,
                                                  unsigned short* __restrict__ Xff) {
  __shared__ float Y[4][2048];  // 32 KB
  const int blk = blockIdx.x;   // 4096 = b*512 + v
  const int b = blk >> 9;
  const int v = blk & 511;
  const int j = threadIdx.x;    // 0..255
  const float* base = x + (size_t)b * 4194304;
  const float* r0 = base + (size_t)v * 2048;
  const float* r1 = base + (size_t)(2047 - v) * 2048;
  const float* r2 = base + (size_t)(1023 - v) * 2048;
  const float* r3 = base + (size_t)(1024 + v) * 2048;

#pragma unroll
  for (int hh = 0; hh < 2; ++hh) {
    const int c = hh * 1024 + 4 * j;
    float4 a = *(const float4*)(r0 + c);
    float4 bb = *(const float4*)(r1 + c);
    float4 cc = *(const float4*)(r2 + c);
    float4 dd = *(const float4*)(r3 + c);
    float4 sp, sm, d0, d1;
    sp.x = (a.x + bb.x) + (cc.x + dd.x); sm.x = (a.x + bb.x) - (cc.x + dd.x);
    sp.y = (a.y + bb.y) + (cc.y + dd.y); sm.y = (a.y + bb.y) - (cc.y + dd.y);
    sp.z = (a.z + bb.z) + (cc.z + dd.z); sm.z = (a.z + bb.z) - (cc.z + dd.z);
    sp.w = (a.w + bb.w) + (cc.w + dd.w); sm.w = (a.w + bb.w) - (cc.w + dd.w);
    d0.x = a.x - bb.x; d1.x = cc.x - dd.x;
    d0.y = a.y - bb.y; d1.y = cc.y - dd.y;
    d0.z = a.z - bb.z; d1.z = cc.z - dd.z;
    d0.w = a.w - bb.w; d1.w = cc.w - dd.w;
    *(float4*)&Y[0][c] = sp;
    *(float4*)&Y[1][c] = sm;
    *(float4*)&Y[2][c] = d0;
    *(float4*)&Y[3][c] = d1;
  }
  __syncthreads();

  unsigned short* orow[4] = {
      Xff + ((size_t)b * 2048 + v) * 2048,
      Xff + ((size_t)b * 2048 + 512 + v) * 2048,
      Xff + ((size_t)b * 2048 + 1024 + v) * 2048,
      Xff + ((size_t)b * 2048 + 2047 - v) * 2048};
  const int c0 = 8 * j;
  int pA, pD, pB, pC, rng;
  if (j < 64) { rng = 0; pA = 8 * j; pD = 2040 - 8 * j; pB = 1016 - 8 * j; pC = 1024 + 8 * j; }
  else if (j < 128) { rng = 1; pA = 8 * j - 512; pD = 2552 - 8 * j; pB = 1528 - 8 * j; pC = 512 + 8 * j; }
  else { rng = 2; pA = 8 * j - 1024; pD = 3064 - 8 * j; pB = 0; pC = 0; }

#pragma unroll
  for (int t = 0; t < 4; ++t) {
    float val[8];
    float4 a0 = *(const float4*)&Y[t][pA];
    float4 a1 = *(const float4*)&Y[t][pA + 4];
    float4 dd0 = *(const float4*)&Y[t][pD];
    float4 dd1 = *(const float4*)&Y[t][pD + 4];
    const float* A0 = (const float*)&a0;
    const float* A1 = (const float*)&a1;
    const float* D0 = (const float*)&dd0;
    const float* D1 = (const float*)&dd1;
    if (rng == 2) {
#pragma unroll
      for (int e = 0; e < 4; ++e) val[e] = A0[e] - D1[3 - e];
#pragma unroll
      for (int e = 4; e < 8; ++e) val[e] = A1[e - 4] - D0[7 - e];
    } else {
      float4 b0 = *(const float4*)&Y[t][pB];
      float4 b1 = *(const float4*)&Y[t][pB + 4];
      float4 cc0 = *(const float4*)&Y[t][pC];
      float4 cc1 = *(const float4*)&Y[t][pC + 4];
      const float* B0 = (const float*)&b0;
      const float* B1 = (const float*)&b1;
      const float* C0 = (const float*)&cc0;
      const float* C1 = (const float*)&cc1;
#pragma unroll
      for (int e = 0; e < 4; ++e) {
        float P = A0[e] + D1[3 - e];
        float M = B1[3 - e] + C0[e];
        val[e] = rng == 0 ? P + M : P - M;
      }
#pragma unroll
      for (int e = 4; e < 8; ++e) {
        float P = A1[e - 4] + D0[7 - e];
        float M = B0[7 - e] + C1[e - 4];
        val[e] = rng == 0 ? P + M : P - M;
      }
    }
    uint4 o = make_uint4(pk2(val[0], val[1]), pk2(val[2], val[3]),
                         pk2(val[4], val[5]), pk2(val[6], val[7]));
    *(uint4*)(orow[t] + c0) = o;
  }
}

// ---- cosine matrices: C4k 1024x1024 (DCT-IV), C2h 512x512, C4h 512x512 ------
__global__ __launch_bounds__(256) void gen_cos3(unsigned short* __restrict__ C4k,
                                                unsigned short* __restrict__ C2h,
                                                unsigned short* __restrict__ C4h) {
  int idx = blockIdx.x * 256 + threadIdx.x;  // 1572864
  const float s = 7.6699039394282061e-4f;    // pi/4096
  if (idx < 1048576) {
    int k = idx >> 10, n = idx & 1023;
    int t = ((2 * n + 1) * (2 * k + 1)) & 8191;   // cos(pi(2n+1)(2k+1)/4096)
    C4k[idx] = f2h_bits(cosf((float)t * s));
  } else if (idx < 1310720) {
    int i2 = idx - 1048576;
    int k = i2 >> 9, n = i2 & 511;
    int t = ((2 * n + 1) * 4 * k) & 8191;         // cos(pi(2n+1)k/1024)
    C2h[i2] = f2h_bits(cosf((float)t * s));
  } else {
    int i2 = idx - 1310720;
    int k = i2 >> 9, n = i2 & 511;
    int t = ((2 * n + 1) * (4 * k + 2)) & 8191;   // cos(pi(2n+1)(2k+1)/2048)
    C4h[i2] = f2h_bits(cosf((float)t * s));
  }
}

// ---- m97-structure GEMM: 128x128 tile, 4 waves, BK=32, single buffer --------
// MODE 0 (stage 1, f16 transposed out U2t[b][ktrue][m2]):
//   SPLIT 0: A cols [1024,2048)=w, B=M0=C4k,  K=1024, ktrue=2c+1
//   SPLIT 1: cls=bnx>>2: A cols cls*512, B=C2h/C4h, K=512, ktrue=4c+2cls
// MODE 1 (stage 2, fp32 out):
//   SPLIT 0: A=C4k (M=1024), B=U2t[z] cols [1024,2048), K=1024, rtrue=2p+1
//   SPLIT 1: cls=bmx>>2: A=C2h/C4h, B=U2t[z] cols cls*512, K=512, rtrue=4p+2cls
template <int MODE, int SPLIT>
__global__ __launch_bounds__(256) void dct_gemm(
    const unsigned short* __restrict__ M0, const unsigned short* __restrict__ M1,
    const unsigned short* __restrict__ D, void* __restrict__ outp) {
  constexpr int K = SPLIT ? 512 : 1024;
  constexpr int NT = K / 32;
  __shared__ unsigned short As[4096];  // 128x32 f16 = 8KB
  __shared__ unsigned short Bs[4096];

  const int tid = threadIdx.x;
  const int lane = tid & 63;
  const int wave = tid >> 6;   // 0..3
  const int wr = wave >> 1;    // 0..1
  const int wc = wave & 1;     // 0..1
  const int bmx = blockIdx.y;
  const int bnx = blockIdx.x;
  const int z = blockIdx.z;

  const unsigned short* Ag;
  const unsigned short* Bg;
  int lda, ldb, arow, brow, cls;
  if (MODE == 0) {
    cls = SPLIT ? (bnx >> 2) : 0;
    Ag = D + (SPLIT ? cls * 512 : 1024);
    lda = 2048;
    arow = bmx * 128;
    Bg = SPLIT ? (cls ? M1 : M0) : M0;
    ldb = K;
    brow = (SPLIT ? (bnx & 3) : bnx) * 128;
  } else {
    cls = SPLIT ? (bmx >> 2) : 0;
    Ag = SPLIT ? (cls ? M1 : M0) : M0;
    lda = K;
    arow = (SPLIT ? (bmx & 3) : bmx) * 128;
    Bg = D + (size_t)z * 4194304u + (SPLIT ? cls * 512 : 1024);
    ldb = 2048;
    brow = bnx * 128;
  }

  const int frc = lane & 15;
  const int cb = (lane >> 4) << 4;

  f32x4 acc[4][4] = {};

  for (int t = 0; t < NT; ++t) {
    stage_tile128(Ag, arow, t * 32, lda, As, wave, lane);
    stage_tile128(Bg, brow, t * 32, ldb, Bs, wave, lane);
    __syncthreads();  // drains vmcnt(0): tile resident for all waves

    half8 af[4], bf[4];
#pragma unroll
    for (int m = 0; m < 4; ++m)
      af[m] = *(const half8*)&As[swz_idx(wr * 64 + m * 16 + frc, cb)];
#pragma unroll
    for (int n = 0; n < 4; ++n)
      bf[n] = *(const half8*)&Bs[swz_idx(wc * 64 + n * 16 + frc, cb)];
#pragma unroll
    for (int m = 0; m < 4; ++m)
#pragma unroll
      for (int n = 0; n < 4; ++n)
        acc[m][n] = __builtin_amdgcn_mfma_f32_16x16x32_f16(af[m], bf[n], acc[m][n], 0, 0, 0);
    __syncthreads();  // all reads done before next iter's stage overwrites
  }

  // epilogue; D mapping: col = lane&15, row = (lane>>4)*4 + i
  if (MODE == 0) {
    unsigned short* U2t = (unsigned short*)outp;
#pragma unroll
    for (int mi = 0; mi < 4; ++mi) {
      const int r = arow + wr * 64 + mi * 16 + (lane >> 4) * 4;
      const int b = r >> 11;
      const int rb = r & 2047;
#pragma unroll
      for (int n = 0; n < 4; ++n) {
        const int ccls = brow + wc * 64 + n * 16 + frc;
        const int ktrue = SPLIT ? (4 * ccls + 2 * cls) : (2 * ccls + 1);
        uint32 lo = f2h_bits(acc[mi][n][0]) | ((uint32)f2h_bits(acc[mi][n][1]) << 16);
        uint32 hi = f2h_bits(acc[mi][n][2]) | ((uint32)f2h_bits(acc[mi][n][3]) << 16);
        *(uint2*)&U2t[(size_t)b * 4194304 + (size_t)ktrue * 2048 + rb] =
            make_uint2(lo, hi);
      }
    }
  } else {
    float* out = (float*)outp + (size_t)z * 4194304;
#pragma unroll
    for (int mi = 0; mi < 4; ++mi) {
      const int p0 = arow + wr * 64 + mi * 16 + (lane >> 4) * 4;
#pragma unroll
      for (int n = 0; n < 4; ++n) {
        const int cg = brow + wc * 64 + n * 16 + frc;
#pragma unroll
        for (int i = 0; i < 4; ++i) {
          const int rtrue = SPLIT ? (4 * (p0 + i) + 2 * cls) : (2 * (p0 + i) + 1);
          out[(size_t)rtrue * 2048 + cg] = acc[mi][n][i];
        }
      }
    }
  }
}

extern "C" void kernel_launch(void* const* d_in, const int* in_sizes, int n_in,
                              void* d_out, int out_size, void* d_ws,
                              size_t ws_size, hipStream_t stream) {
  const float* x = (const float*)d_in[0];
  float* out = (float*)d_out;

  // workspace (f16 elems):
  // Xff 33554432 | C4k 1048576 | C2h 262144 | C4h 262144 | U2t 33554432
  unsigned short* Xff = (unsigned short*)d_ws;
  unsigned short* C4k = Xff + 33554432u;
  unsigned short* C2h = C4k + 1048576u;
  unsigned short* C4h = C2h + 262144u;
  unsigned short* U2t = C4h + 262144u;

  cvt_fold22<<<4096, 256, 0, stream>>>(x, Xff);  // one block per (b,v): 8*512
  gen_cos3<<<6144, 256, 0, stream>>>(C4k, C2h, C4h);
  // stage 1: odd k (K=1024) and even k (K=512, u+/u- classes)
  dct_gemm<0, 0><<<dim3(8, 128, 1), 256, 0, stream>>>(C4k, C4k, Xff, (void*)U2t);
  dct_gemm<0, 1><<<dim3(8, 128, 1), 256, 0, stream>>>(C2h, C4h, Xff, (void*)U2t);
  // stage 2: odd rows (K=1024) and even rows (K=512)
  dct_gemm<1, 0><<<dim3(16, 8, 8), 256, 0, stream>>>(C4k, C4k, U2t, (void*)out);
  dct_gemm<1, 1><<<dim3(16, 8, 8), 256, 0, stream>>>(C2h, C4h, U2t, (void*)out);
}

// Round 14
// 191.205 us; speedup vs baseline: 1.1786x; 1.1786x over previous
//
#include <hip/hip_runtime.h>
#include <hip/hip_bf16.h>
#include <hip/hip_fp16.h>

// 2D DCT-II via LEVEL-2 folded f16 MFMA GEMMs.
// Per 2048-DCT: k odd -> DCT4-1024 on w (K=1024); k=4s -> DCT2-512 on u+
// (K=512); k=4s+2 -> DCT4-512 on u- (K=512). MACs = 0.75x of level-1.
// R14: GEMM reverted to R11's proven 256x256/8-wave/4-buffer/depth-2 ring
// (R13's 128^2 single-buffer regressed 225us). NEW: bijective XCD-chunked
// block swizzle (T1/m204) on all 4 GEMM dispatches - each XCD gets a
// contiguous f-range (stage1: 8 bm-rows -> A-slab fetched once per XCD;
// stage2: one batch z -> U2t panel fetched once). Targets the measured
// FETCH_SIZE 135MB (ideal ~50) at 2.3TB/s. All grids = 256 wgs, 8 | 256.
// cvt/gen unchanged from R11.

typedef _Float16 half8 __attribute__((ext_vector_type(8)));
typedef float f32x4 __attribute__((ext_vector_type(4)));
typedef unsigned int uint32;

constexpr int TILE_E = 256 * 32;  // 8192 f16 = 16KB

__device__ __forceinline__ unsigned short f2h_bits(float f) {
  _Float16 h = (_Float16)f;
  return __builtin_bit_cast(unsigned short, h);
}
__device__ __forceinline__ uint32 pk2(float a, float b) {
  return f2h_bits(a) | ((uint32)f2h_bits(b) << 16);
}

__device__ __forceinline__ void gload_lds16(const unsigned short* g, unsigned short* l) {
  __builtin_amdgcn_global_load_lds((const __attribute__((address_space(1))) void*)g,
                                   (__attribute__((address_space(3))) void*)l,
                                   16, 0, 0);
}

#define CFENCE asm volatile("" ::: "memory")

// Stored f16 index for logical (tile row r, 16B k-slot byte cb); stored rows
// are 128B (two logical rows); slot' = ((r&1)<<2 | cb>>4) ^ ((r>>1)&7).
// Measured 0 bank conflicts (R2-R12).
__device__ __forceinline__ int swz_idx(int r, int cbyte) {
  int b = (r >> 1) * 128 + ((((r & 1) << 6) | cbyte) ^ (((r >> 1) & 7) << 4));
  return b >> 1;
}

// Stage a 256x32 f16 tile from G (row-major, stride ld); LDS dest LINEAR,
// swizzle realized by inverse-permuting per-lane global source addresses.
__device__ __forceinline__ void stage_tile(const unsigned short* __restrict__ G,
                                           int rowbase, int k0, int ld,
                                           unsigned short* lds, int wave, int lane) {
#pragma unroll
  for (int c = 0; c < 2; ++c) {
    const int p = c * 64 + wave * 8 + (lane >> 3);   // stored 128B row
    const int v = (lane & 7) ^ ((lane >> 3) & 7);    // inverse slot swizzle
    const int r = 2 * p + (v >> 2);                  // logical tile row
    const int kslot = v & 3;
    const unsigned short* src = G + (size_t)(rowbase + r) * ld + (k0 + kslot * 8);
    unsigned short* dst = lds + (c * 64 + wave * 8) * 64;  // wave-uniform
    gload_lds16(src, dst);
  }
}

// ---- convert + FULL 2-level 2D fold, LDS-bounce (R11, unchanged) ------------
__global__ __launch_bounds__(256) void cvt_fold22(const float* __restrict__ x,
                                                  unsigned short* __restrict__ Xff) {
  __shared__ float Y[4][2048];  // 32 KB
  const int blk = blockIdx.x;   // 4096 = b*512 + v
  const int b = blk >> 9;
  const int v = blk & 511;
  const int j = threadIdx.x;    // 0..255
  const float* base = x + (size_t)b * 4194304;
  const float* r0 = base + (size_t)v * 2048;
  const float* r1 = base + (size_t)(2047 - v) * 2048;
  const float* r2 = base + (size_t)(1023 - v) * 2048;
  const float* r3 = base + (size_t)(1024 + v) * 2048;

#pragma unroll
  for (int hh = 0; hh < 2; ++hh) {
    const int c = hh * 1024 + 4 * j;
    float4 a = *(const float4*)(r0 + c);
    float4 bb = *(const float4*)(r1 + c);
    float4 cc = *(const float4*)(r2 + c);
    float4 dd = *(const float4*)(r3 + c);
    float4 sp, sm, d0, d1;
    sp.x = (a.x + bb.x) + (cc.x + dd.x); sm.x = (a.x + bb.x) - (cc.x + dd.x);
    sp.y = (a.y + bb.y) + (cc.y + dd.y); sm.y = (a.y + bb.y) - (cc.y + dd.y);
    sp.z = (a.z + bb.z) + (cc.z + dd.z); sm.z = (a.z + bb.z) - (cc.z + dd.z);
    sp.w = (a.w + bb.w) + (cc.w + dd.w); sm.w = (a.w + bb.w) - (cc.w + dd.w);
    d0.x = a.x - bb.x; d1.x = cc.x - dd.x;
    d0.y = a.y - bb.y; d1.y = cc.y - dd.y;
    d0.z = a.z - bb.z; d1.z = cc.z - dd.z;
    d0.w = a.w - bb.w; d1.w = cc.w - dd.w;
    *(float4*)&Y[0][c] = sp;
    *(float4*)&Y[1][c] = sm;
    *(float4*)&Y[2][c] = d0;
    *(float4*)&Y[3][c] = d1;
  }
  __syncthreads();

  unsigned short* orow[4] = {
      Xff + ((size_t)b * 2048 + v) * 2048,
      Xff + ((size_t)b * 2048 + 512 + v) * 2048,
      Xff + ((size_t)b * 2048 + 1024 + v) * 2048,
      Xff + ((size_t)b * 2048 + 2047 - v) * 2048};
  const int c0 = 8 * j;
  int pA, pD, pB, pC, rng;
  if (j < 64) { rng = 0; pA = 8 * j; pD = 2040 - 8 * j; pB = 1016 - 8 * j; pC = 1024 + 8 * j; }
  else if (j < 128) { rng = 1; pA = 8 * j - 512; pD = 2552 - 8 * j; pB = 1528 - 8 * j; pC = 512 + 8 * j; }
  else { rng = 2; pA = 8 * j - 1024; pD = 3064 - 8 * j; pB = 0; pC = 0; }

#pragma unroll
  for (int t = 0; t < 4; ++t) {
    float val[8];
    float4 a0 = *(const float4*)&Y[t][pA];
    float4 a1 = *(const float4*)&Y[t][pA + 4];
    float4 dd0 = *(const float4*)&Y[t][pD];
    float4 dd1 = *(const float4*)&Y[t][pD + 4];
    const float* A0 = (const float*)&a0;
    const float* A1 = (const float*)&a1;
    const float* D0 = (const float*)&dd0;
    const float* D1 = (const float*)&dd1;
    if (rng == 2) {
#pragma unroll
      for (int e = 0; e < 4; ++e) val[e] = A0[e] - D1[3 - e];
#pragma unroll
      for (int e = 4; e < 8; ++e) val[e] = A1[e - 4] - D0[7 - e];
    } else {
      float4 b0 = *(const float4*)&Y[t][pB];
      float4 b1 = *(const float4*)&Y[t][pB + 4];
      float4 cc0 = *(const float4*)&Y[t][pC];
      float4 cc1 = *(const float4*)&Y[t][pC + 4];
      const float* B0 = (const float*)&b0;
      const float* B1 = (const float*)&b1;
      const float* C0 = (const float*)&cc0;
      const float* C1 = (const float*)&cc1;
#pragma unroll
      for (int e = 0; e < 4; ++e) {
        float P = A0[e] + D1[3 - e];
        float M = B1[3 - e] + C0[e];
        val[e] = rng == 0 ? P + M : P - M;
      }
#pragma unroll
      for (int e = 4; e < 8; ++e) {
        float P = A1[e - 4] + D0[7 - e];
        float M = B0[7 - e] + C1[e - 4];
        val[e] = rng == 0 ? P + M : P - M;
      }
    }
    uint4 o = make_uint4(pk2(val[0], val[1]), pk2(val[2], val[3]),
                         pk2(val[4], val[5]), pk2(val[6], val[7]));
    *(uint4*)(orow[t] + c0) = o;
  }
}

// ---- cosine matrices: C4k 1024x1024 (DCT-IV), C2h 512x512, C4h 512x512 ------
__global__ __launch_bounds__(256) void gen_cos3(unsigned short* __restrict__ C4k,
                                                unsigned short* __restrict__ C2h,
                                                unsigned short* __restrict__ C4h) {
  int idx = blockIdx.x * 256 + threadIdx.x;  // 1572864
  const float s = 7.6699039394282061e-4f;    // pi/4096
  if (idx < 1048576) {
    int k = idx >> 10, n = idx & 1023;
    int t = ((2 * n + 1) * (2 * k + 1)) & 8191;   // cos(pi(2n+1)(2k+1)/4096)
    C4k[idx] = f2h_bits(cosf((float)t * s));
  } else if (idx < 1310720) {
    int i2 = idx - 1048576;
    int k = i2 >> 9, n = i2 & 511;
    int t = ((2 * n + 1) * 4 * k) & 8191;         // cos(pi(2n+1)k/1024)
    C2h[i2] = f2h_bits(cosf((float)t * s));
  } else {
    int i2 = idx - 1310720;
    int k = i2 >> 9, n = i2 & 511;
    int t = ((2 * n + 1) * (4 * k + 2)) & 8191;   // cos(pi(2n+1)(2k+1)/2048)
    C4h[i2] = f2h_bits(cosf((float)t * s));
  }
}

// ---- pipelined GEMM (R11 structure) + bijective XCD chunk swizzle -----------
// Grids are compile-time per instantiation: MODE0 (4,64,1), MODE1 (8,4,8);
// nwg=256, q=32. f = (lin%8)*32 + lin/8 gives XCD c the contiguous f-range
// [32c,32c+32): MODE0 -> bm-rows [8c,8c+8) (A-slab shared in-XCD);
// MODE1 -> one batch z=c per XCD (U2t panel shared in-XCD).
template <int MODE, int SPLIT>
__global__ __launch_bounds__(512) void dct_gemm(
    const unsigned short* __restrict__ M0, const unsigned short* __restrict__ M1,
    const unsigned short* __restrict__ D, void* __restrict__ outp) {
  constexpr int K = SPLIT ? 512 : 1024;
  constexpr int NT = K / 32;
  __shared__ unsigned short As[4 * TILE_E];
  __shared__ unsigned short Bs[4 * TILE_E];

  const int tid = threadIdx.x;
  const int lane = tid & 63;
  const int wave = tid >> 6;
  const int wr = wave >> 2;
  const int wc = wave & 3;

  // XCD-chunked bijective remap (nwg = 256 for all instantiations)
  int lin, f, bmx, bnx, z;
  if (MODE == 0) {
    lin = blockIdx.y * 4 + blockIdx.x;            // gx=4, gy=64
    f = (lin & 7) * 32 + (lin >> 3);
    bnx = f & 3;
    bmx = f >> 2;
    z = 0;
  } else {
    lin = (blockIdx.z * 4 + blockIdx.y) * 8 + blockIdx.x;  // gx=8, gy=4, gz=8
    f = (lin & 7) * 32 + (lin >> 3);
    bnx = f & 7;
    bmx = (f >> 3) & 3;
    z = f >> 5;
  }

  const unsigned short* Ag;
  const unsigned short* Bg;
  int lda, ldb, arow, brow, cls;
  if (MODE == 0) {
    cls = SPLIT ? (bnx >> 1) : 0;
    Ag = D + (SPLIT ? cls * 512 : 1024);
    lda = 2048;
    arow = bmx * 256;
    Bg = SPLIT ? (cls ? M1 : M0) : M0;
    ldb = K;
    brow = (SPLIT ? (bnx & 1) : bnx) * 256;
  } else {
    cls = SPLIT ? (bmx >> 1) : 0;
    Ag = SPLIT ? (cls ? M1 : M0) : M0;
    lda = K;
    arow = (SPLIT ? (bmx & 1) : bmx) * 256;
    Bg = D + (size_t)z * 4194304u + (SPLIT ? cls * 512 : 1024);
    ldb = 2048;
    brow = bnx * 256;
  }

  const int frc = lane & 15;
  const int cb = (lane >> 4) << 4;

  f32x4 acc[8][4] = {};

  stage_tile(Ag, arow, 0, lda, &As[0], wave, lane);
  stage_tile(Bg, brow, 0, ldb, &Bs[0], wave, lane);
  stage_tile(Ag, arow, 32, lda, &As[TILE_E], wave, lane);
  stage_tile(Bg, brow, 32, ldb, &Bs[TILE_E], wave, lane);
  asm volatile("s_waitcnt vmcnt(4)" ::: "memory");
  CFENCE; __builtin_amdgcn_s_barrier(); CFENCE;

  for (int t = 0; t < NT; ++t) {
    const unsigned short* at = &As[(t & 3) * TILE_E];
    const unsigned short* bt = &Bs[(t & 3) * TILE_E];
    half8 af[4], bf[4];

    // phase 1: reads (quadrant mh=0) + stage A(t+2)
#pragma unroll
    for (int m = 0; m < 4; ++m)
      af[m] = *(const half8*)&at[swz_idx(wr * 128 + m * 16 + frc, cb)];
#pragma unroll
    for (int n = 0; n < 4; ++n)
      bf[n] = *(const half8*)&bt[swz_idx(wc * 64 + n * 16 + frc, cb)];
    if (t + 2 < NT)
      stage_tile(Ag, arow, (t + 2) * 32, lda, &As[((t + 2) & 3) * TILE_E], wave, lane);
    CFENCE; __builtin_amdgcn_s_barrier(); CFENCE;
    __builtin_amdgcn_s_setprio(1);
#pragma unroll
    for (int m = 0; m < 4; ++m)
#pragma unroll
      for (int n = 0; n < 4; ++n)
        acc[m][n] = __builtin_amdgcn_mfma_f32_16x16x32_f16(af[m], bf[n], acc[m][n], 0, 0, 0);
    __builtin_amdgcn_s_setprio(0);

    // phase 2: reads (quadrant mh=1) + stage B(t+2) + counted boundary
#pragma unroll
    for (int m = 0; m < 4; ++m)
      af[m] = *(const half8*)&at[swz_idx(wr * 128 + 64 + m * 16 + frc, cb)];
    if (t + 2 < NT)
      stage_tile(Bg, brow, (t + 2) * 32, ldb, &Bs[((t + 2) & 3) * TILE_E], wave, lane);
    if (t < NT - 2)
      asm volatile("s_waitcnt vmcnt(4)" ::: "memory");
    else if (t == NT - 2)
      asm volatile("s_waitcnt vmcnt(0)" ::: "memory");
    CFENCE; __builtin_amdgcn_s_barrier(); CFENCE;
    __builtin_amdgcn_s_setprio(1);
#pragma unroll
    for (int m = 0; m < 4; ++m)
#pragma unroll
      for (int n = 0; n < 4; ++n)
        acc[m + 4][n] =
            __builtin_amdgcn_mfma_f32_16x16x32_f16(af[m], bf[n], acc[m + 4][n], 0, 0, 0);
    __builtin_amdgcn_s_setprio(0);
  }

  // epilogue; D mapping: col = lane&15, row = (lane>>4)*4 + i
  if (MODE == 0) {
    unsigned short* U2t = (unsigned short*)outp;
#pragma unroll
    for (int mi = 0; mi < 8; ++mi) {
      const int r = arow + wr * 128 + (mi >> 2) * 64 + (mi & 3) * 16 + (lane >> 4) * 4;
      const int b = r >> 11;
      const int rb = r & 2047;
#pragma unroll
      for (int n = 0; n < 4; ++n) {
        const int ccls = brow + wc * 64 + n * 16 + frc;
        const int ktrue = SPLIT ? (4 * ccls + 2 * cls) : (2 * ccls + 1);
        uint32 lo = f2h_bits(acc[mi][n][0]) | ((uint32)f2h_bits(acc[mi][n][1]) << 16);
        uint32 hi = f2h_bits(acc[mi][n][2]) | ((uint32)f2h_bits(acc[mi][n][3]) << 16);
        *(uint2*)&U2t[(size_t)b * 4194304 + (size_t)ktrue * 2048 + rb] =
            make_uint2(lo, hi);
      }
    }
  } else {
    float* out = (float*)outp + (size_t)z * 4194304;
#pragma unroll
    for (int mi = 0; mi < 8; ++mi) {
      const int p0 = arow + wr * 128 + (mi >> 2) * 64 + (mi & 3) * 16 + (lane >> 4) * 4;
#pragma unroll
      for (int n = 0; n < 4; ++n) {
        const int cg = brow + wc * 64 + n * 16 + frc;
#pragma unroll
        for (int i = 0; i < 4; ++i) {
          const int rtrue = SPLIT ? (4 * (p0 + i) + 2 * cls) : (2 * (p0 + i) + 1);
          out[(size_t)rtrue * 2048 + cg] = acc[mi][n][i];
        }
      }
    }
  }
}

extern "C" void kernel_launch(void* const* d_in, const int* in_sizes, int n_in,
                              void* d_out, int out_size, void* d_ws,
                              size_t ws_size, hipStream_t stream) {
  const float* x = (const float*)d_in[0];
  float* out = (float*)d_out;

  // workspace (f16 elems):
  // Xff 33554432 | C4k 1048576 | C2h 262144 | C4h 262144 | U2t 33554432
  unsigned short* Xff = (unsigned short*)d_ws;
  unsigned short* C4k = Xff + 33554432u;
  unsigned short* C2h = C4k + 1048576u;
  unsigned short* C4h = C2h + 262144u;
  unsigned short* U2t = C4h + 262144u;

  cvt_fold22<<<4096, 256, 0, stream>>>(x, Xff);  // one block per (b,v): 8*512
  gen_cos3<<<6144, 256, 0, stream>>>(C4k, C2h, C4h);
  // stage 1: odd k (K=1024) and even k (K=512, u+/u- classes)
  dct_gemm<0, 0><<<dim3(4, 64, 1), 512, 0, stream>>>(C4k, C4k, Xff, (void*)U2t);
  dct_gemm<0, 1><<<dim3(4, 64, 1), 512, 0, stream>>>(C2h, C4h, Xff, (void*)U2t);
  // stage 2: odd rows (K=1024) and even rows (K=512)
  dct_gemm<1, 0><<<dim3(8, 4, 8), 512, 0, stream>>>(C4k, C4k, U2t, (void*)out);
  dct_gemm<1, 1><<<dim3(8, 4, 8), 512, 0, stream>>>(C2h, C4h, U2t, (void*)out);
}

// Round 15
// 190.058 us; speedup vs baseline: 1.1857x; 1.0060x over previous
//
#include <hip/hip_runtime.h>
#include <hip/hip_bf16.h>
#include <hip/hip_fp16.h>

// 2D DCT-II via LEVEL-2 folded f16 MFMA GEMMs.
// Per 2048-DCT: k odd -> DCT4-1024 on w (K=1024); k=4s -> DCT2-512 on u+
// (K=512); k=4s+2 -> DCT4-512 on u- (K=512). MACs = 0.75x of level-1.
// R15 change (cvt only): R11's phase-2 read pattern was a 16-way LDS bank
// conflict (8 cols/thread -> 32B lane stride on every float4 read; ~8700 cy
// of LDS-unit time per block vs 4800 cy BW floor). Now 512 thr/block with
// 4 cols/thread: all phase-2 reads are 16B-lane-stride float4 (2 lanes/bank
// = free, m136), stores uint2 full-density ascending. GEMMs = R14 verbatim
// (256^2 8-wave 4-buffer ring + bijective XCD chunk swizzle, 191.2us).

typedef _Float16 half8 __attribute__((ext_vector_type(8)));
typedef float f32x4 __attribute__((ext_vector_type(4)));
typedef unsigned int uint32;

constexpr int TILE_E = 256 * 32;  // 8192 f16 = 16KB

__device__ __forceinline__ unsigned short f2h_bits(float f) {
  _Float16 h = (_Float16)f;
  return __builtin_bit_cast(unsigned short, h);
}
__device__ __forceinline__ uint32 pk2(float a, float b) {
  return f2h_bits(a) | ((uint32)f2h_bits(b) << 16);
}

__device__ __forceinline__ void gload_lds16(const unsigned short* g, unsigned short* l) {
  __builtin_amdgcn_global_load_lds((const __attribute__((address_space(1))) void*)g,
                                   (__attribute__((address_space(3))) void*)l,
                                   16, 0, 0);
}

#define CFENCE asm volatile("" ::: "memory")

// Stored f16 index for logical (tile row r, 16B k-slot byte cb); stored rows
// are 128B (two logical rows); slot' = ((r&1)<<2 | cb>>4) ^ ((r>>1)&7).
// Measured 0 bank conflicts (R2-R14).
__device__ __forceinline__ int swz_idx(int r, int cbyte) {
  int b = (r >> 1) * 128 + ((((r & 1) << 6) | cbyte) ^ (((r >> 1) & 7) << 4));
  return b >> 1;
}

// Stage a 256x32 f16 tile from G (row-major, stride ld); LDS dest LINEAR,
// swizzle realized by inverse-permuting per-lane global source addresses.
__device__ __forceinline__ void stage_tile(const unsigned short* __restrict__ G,
                                           int rowbase, int k0, int ld,
                                           unsigned short* lds, int wave, int lane) {
#pragma unroll
  for (int c = 0; c < 2; ++c) {
    const int p = c * 64 + wave * 8 + (lane >> 3);   // stored 128B row
    const int v = (lane & 7) ^ ((lane >> 3) & 7);    // inverse slot swizzle
    const int r = 2 * p + (v >> 2);                  // logical tile row
    const int kslot = v & 3;
    const unsigned short* src = G + (size_t)(rowbase + r) * ld + (k0 + kslot * 8);
    unsigned short* dst = lds + (c * 64 + wave * 8) * 64;  // wave-uniform
    gload_lds16(src, dst);
  }
}

// ---- convert + FULL 2-level 2D fold, LDS-bounce, conflict-free --------------
// Block = (b, v), 512 threads. Input rows {v, 2047-v, 1023-v, 1024+v};
// Y0=Sp=(r0+r1)+(r2+r3), Y1=Sm=(r0+r1)-(r2+r3), Y2=r0-r1, Y3=r2-r3 in LDS.
// Output rows {v, 512+v, 1024+v, 2047-v} = col-fold of Y0..Y3:
//   col c<512:        (Y[c]+Y[2047-c]) + (Y[1023-c]+Y[1024+c])
//   col 512<=c<1024:  n=c-512: (Y[n]+Y[2047-n]) - (Y[1023-n]+Y[1024+n])
//   col c>=1024:      q=c-1024: Y[q] - Y[2047-q]
// Thread j owns 4 cols [4j,4j+4): every LDS read is a float4 at 16B lane
// stride (conflict-free); every global store uint2 ascending full-density.
__global__ __launch_bounds__(512) void cvt_fold22(const float* __restrict__ x,
                                                  unsigned short* __restrict__ Xff) {
  __shared__ float Y[4][2048];  // 32 KB
  const int blk = blockIdx.x;   // 4096 = b*512 + v
  const int b = blk >> 9;
  const int v = blk & 511;
  const int j = threadIdx.x;    // 0..511
  const float* base = x + (size_t)b * 4194304;
  const float* r0 = base + (size_t)v * 2048;
  const float* r1 = base + (size_t)(2047 - v) * 2048;
  const float* r2 = base + (size_t)(1023 - v) * 2048;
  const float* r3 = base + (size_t)(1024 + v) * 2048;

  // phase 1: one float4 col-chunk per thread per row (c = 4j)
  {
    const int c = 4 * j;
    float4 a = *(const float4*)(r0 + c);
    float4 bb = *(const float4*)(r1 + c);
    float4 cc = *(const float4*)(r2 + c);
    float4 dd = *(const float4*)(r3 + c);
    float4 sp, sm, d0, d1;
    sp.x = (a.x + bb.x) + (cc.x + dd.x); sm.x = (a.x + bb.x) - (cc.x + dd.x);
    sp.y = (a.y + bb.y) + (cc.y + dd.y); sm.y = (a.y + bb.y) - (cc.y + dd.y);
    sp.z = (a.z + bb.z) + (cc.z + dd.z); sm.z = (a.z + bb.z) - (cc.z + dd.z);
    sp.w = (a.w + bb.w) + (cc.w + dd.w); sm.w = (a.w + bb.w) - (cc.w + dd.w);
    d0.x = a.x - bb.x; d1.x = cc.x - dd.x;
    d0.y = a.y - bb.y; d1.y = cc.y - dd.y;
    d0.z = a.z - bb.z; d1.z = cc.z - dd.z;
    d0.w = a.w - bb.w; d1.w = cc.w - dd.w;
    *(float4*)&Y[0][c] = sp;
    *(float4*)&Y[1][c] = sm;
    *(float4*)&Y[2][c] = d0;
    *(float4*)&Y[3][c] = d1;
  }
  __syncthreads();

  // phase 2: thread j -> output cols [4j, 4j+4) for all 4 output rows
  unsigned short* orow[4] = {
      Xff + ((size_t)b * 2048 + v) * 2048,
      Xff + ((size_t)b * 2048 + 512 + v) * 2048,
      Xff + ((size_t)b * 2048 + 1024 + v) * 2048,
      Xff + ((size_t)b * 2048 + 2047 - v) * 2048};
  const int c0 = 4 * j;
  int pA, pD, pB, pC, rng;
  if (j < 128) { rng = 0; pA = 4 * j; pD = 2044 - 4 * j; pB = 1020 - 4 * j; pC = 1024 + 4 * j; }
  else if (j < 256) { rng = 1; pA = 4 * j - 512; pD = 2556 - 4 * j; pB = 1532 - 4 * j; pC = 512 + 4 * j; }
  else { rng = 2; pA = 4 * j - 1024; pD = 3068 - 4 * j; pB = 0; pC = 0; }

#pragma unroll
  for (int t = 0; t < 4; ++t) {
    float val[4];
    float4 av = *(const float4*)&Y[t][pA];
    float4 dv = *(const float4*)&Y[t][pD];
    const float* A = (const float*)&av;
    const float* Dq = (const float*)&dv;
    if (rng == 2) {
#pragma unroll
      for (int e = 0; e < 4; ++e) val[e] = A[e] - Dq[3 - e];
    } else {
      float4 bv = *(const float4*)&Y[t][pB];
      float4 cv = *(const float4*)&Y[t][pC];
      const float* Bq = (const float*)&bv;
      const float* Cq = (const float*)&cv;
#pragma unroll
      for (int e = 0; e < 4; ++e) {
        float P = A[e] + Dq[3 - e];
        float M = Bq[3 - e] + Cq[e];
        val[e] = rng == 0 ? P + M : P - M;
      }
    }
    *(uint2*)(orow[t] + c0) = make_uint2(pk2(val[0], val[1]), pk2(val[2], val[3]));
  }
}

// ---- cosine matrices: C4k 1024x1024 (DCT-IV), C2h 512x512, C4h 512x512 ------
__global__ __launch_bounds__(256) void gen_cos3(unsigned short* __restrict__ C4k,
                                                unsigned short* __restrict__ C2h,
                                                unsigned short* __restrict__ C4h) {
  int idx = blockIdx.x * 256 + threadIdx.x;  // 1572864
  const float s = 7.6699039394282061e-4f;    // pi/4096
  if (idx < 1048576) {
    int k = idx >> 10, n = idx & 1023;
    int t = ((2 * n + 1) * (2 * k + 1)) & 8191;   // cos(pi(2n+1)(2k+1)/4096)
    C4k[idx] = f2h_bits(cosf((float)t * s));
  } else if (idx < 1310720) {
    int i2 = idx - 1048576;
    int k = i2 >> 9, n = i2 & 511;
    int t = ((2 * n + 1) * 4 * k) & 8191;         // cos(pi(2n+1)k/1024)
    C2h[i2] = f2h_bits(cosf((float)t * s));
  } else {
    int i2 = idx - 1310720;
    int k = i2 >> 9, n = i2 & 511;
    int t = ((2 * n + 1) * (4 * k + 2)) & 8191;   // cos(pi(2n+1)(2k+1)/2048)
    C4h[i2] = f2h_bits(cosf((float)t * s));
  }
}

// ---- pipelined GEMM (R11 structure) + bijective XCD chunk swizzle -----------
// Grids are compile-time per instantiation: MODE0 (4,64,1), MODE1 (8,4,8);
// nwg=256, q=32. f = (lin%8)*32 + lin/8 gives XCD c the contiguous f-range
// [32c,32c+32): MODE0 -> bm-rows [8c,8c+8) (A-slab shared in-XCD);
// MODE1 -> one batch z=c per XCD (U2t panel shared in-XCD).
template <int MODE, int SPLIT>
__global__ __launch_bounds__(512) void dct_gemm(
    const unsigned short* __restrict__ M0, const unsigned short* __restrict__ M1,
    const unsigned short* __restrict__ D, void* __restrict__ outp) {
  constexpr int K = SPLIT ? 512 : 1024;
  constexpr int NT = K / 32;
  __shared__ unsigned short As[4 * TILE_E];
  __shared__ unsigned short Bs[4 * TILE_E];

  const int tid = threadIdx.x;
  const int lane = tid & 63;
  const int wave = tid >> 6;
  const int wr = wave >> 2;
  const int wc = wave & 3;

  // XCD-chunked bijective remap (nwg = 256 for all instantiations)
  int lin, f, bmx, bnx, z;
  if (MODE == 0) {
    lin = blockIdx.y * 4 + blockIdx.x;            // gx=4, gy=64
    f = (lin & 7) * 32 + (lin >> 3);
    bnx = f & 3;
    bmx = f >> 2;
    z = 0;
  } else {
    lin = (blockIdx.z * 4 + blockIdx.y) * 8 + blockIdx.x;  // gx=8, gy=4, gz=8
    f = (lin & 7) * 32 + (lin >> 3);
    bnx = f & 7;
    bmx = (f >> 3) & 3;
    z = f >> 5;
  }

  const unsigned short* Ag;
  const unsigned short* Bg;
  int lda, ldb, arow, brow, cls;
  if (MODE == 0) {
    cls = SPLIT ? (bnx >> 1) : 0;
    Ag = D + (SPLIT ? cls * 512 : 1024);
    lda = 2048;
    arow = bmx * 256;
    Bg = SPLIT ? (cls ? M1 : M0) : M0;
    ldb = K;
    brow = (SPLIT ? (bnx & 1) : bnx) * 256;
  } else {
    cls = SPLIT ? (bmx >> 1) : 0;
    Ag = SPLIT ? (cls ? M1 : M0) : M0;
    lda = K;
    arow = (SPLIT ? (bmx & 1) : bmx) * 256;
    Bg = D + (size_t)z * 4194304u + (SPLIT ? cls * 512 : 1024);
    ldb = 2048;
    brow = bnx * 256;
  }

  const int frc = lane & 15;
  const int cb = (lane >> 4) << 4;

  f32x4 acc[8][4] = {};

  stage_tile(Ag, arow, 0, lda, &As[0], wave, lane);
  stage_tile(Bg, brow, 0, ldb, &Bs[0], wave, lane);
  stage_tile(Ag, arow, 32, lda, &As[TILE_E], wave, lane);
  stage_tile(Bg, brow, 32, ldb, &Bs[TILE_E], wave, lane);
  asm volatile("s_waitcnt vmcnt(4)" ::: "memory");
  CFENCE; __builtin_amdgcn_s_barrier(); CFENCE;

  for (int t = 0; t < NT; ++t) {
    const unsigned short* at = &As[(t & 3) * TILE_E];
    const unsigned short* bt = &Bs[(t & 3) * TILE_E];
    half8 af[4], bf[4];

    // phase 1: reads (quadrant mh=0) + stage A(t+2)
#pragma unroll
    for (int m = 0; m < 4; ++m)
      af[m] = *(const half8*)&at[swz_idx(wr * 128 + m * 16 + frc, cb)];
#pragma unroll
    for (int n = 0; n < 4; ++n)
      bf[n] = *(const half8*)&bt[swz_idx(wc * 64 + n * 16 + frc, cb)];
    if (t + 2 < NT)
      stage_tile(Ag, arow, (t + 2) * 32, lda, &As[((t + 2) & 3) * TILE_E], wave, lane);
    CFENCE; __builtin_amdgcn_s_barrier(); CFENCE;
    __builtin_amdgcn_s_setprio(1);
#pragma unroll
    for (int m = 0; m < 4; ++m)
#pragma unroll
      for (int n = 0; n < 4; ++n)
        acc[m][n] = __builtin_amdgcn_mfma_f32_16x16x32_f16(af[m], bf[n], acc[m][n], 0, 0, 0);
    __builtin_amdgcn_s_setprio(0);

    // phase 2: reads (quadrant mh=1) + stage B(t+2) + counted boundary
#pragma unroll
    for (int m = 0; m < 4; ++m)
      af[m] = *(const half8*)&at[swz_idx(wr * 128 + 64 + m * 16 + frc, cb)];
    if (t + 2 < NT)
      stage_tile(Bg, brow, (t + 2) * 32, ldb, &Bs[((t + 2) & 3) * TILE_E], wave, lane);
    if (t < NT - 2)
      asm volatile("s_waitcnt vmcnt(4)" ::: "memory");
    else if (t == NT - 2)
      asm volatile("s_waitcnt vmcnt(0)" ::: "memory");
    CFENCE; __builtin_amdgcn_s_barrier(); CFENCE;
    __builtin_amdgcn_s_setprio(1);
#pragma unroll
    for (int m = 0; m < 4; ++m)
#pragma unroll
      for (int n = 0; n < 4; ++n)
        acc[m + 4][n] =
            __builtin_amdgcn_mfma_f32_16x16x32_f16(af[m], bf[n], acc[m + 4][n], 0, 0, 0);
    __builtin_amdgcn_s_setprio(0);
  }

  // epilogue; D mapping: col = lane&15, row = (lane>>4)*4 + i
  if (MODE == 0) {
    unsigned short* U2t = (unsigned short*)outp;
#pragma unroll
    for (int mi = 0; mi < 8; ++mi) {
      const int r = arow + wr * 128 + (mi >> 2) * 64 + (mi & 3) * 16 + (lane >> 4) * 4;
      const int b = r >> 11;
      const int rb = r & 2047;
#pragma unroll
      for (int n = 0; n < 4; ++n) {
        const int ccls = brow + wc * 64 + n * 16 + frc;
        const int ktrue = SPLIT ? (4 * ccls + 2 * cls) : (2 * ccls + 1);
        uint32 lo = f2h_bits(acc[mi][n][0]) | ((uint32)f2h_bits(acc[mi][n][1]) << 16);
        uint32 hi = f2h_bits(acc[mi][n][2]) | ((uint32)f2h_bits(acc[mi][n][3]) << 16);
        *(uint2*)&U2t[(size_t)b * 4194304 + (size_t)ktrue * 2048 + rb] =
            make_uint2(lo, hi);
      }
    }
  } else {
    float* out = (float*)outp + (size_t)z * 4194304;
#pragma unroll
    for (int mi = 0; mi < 8; ++mi) {
      const int p0 = arow + wr * 128 + (mi >> 2) * 64 + (mi & 3) * 16 + (lane >> 4) * 4;
#pragma unroll
      for (int n = 0; n < 4; ++n) {
        const int cg = brow + wc * 64 + n * 16 + frc;
#pragma unroll
        for (int i = 0; i < 4; ++i) {
          const int rtrue = SPLIT ? (4 * (p0 + i) + 2 * cls) : (2 * (p0 + i) + 1);
          out[(size_t)rtrue * 2048 + cg] = acc[mi][n][i];
        }
      }
    }
  }
}

extern "C" void kernel_launch(void* const* d_in, const int* in_sizes, int n_in,
                              void* d_out, int out_size, void* d_ws,
                              size_t ws_size, hipStream_t stream) {
  const float* x = (const float*)d_in[0];
  float* out = (float*)d_out;

  // workspace (f16 elems):
  // Xff 33554432 | C4k 1048576 | C2h 262144 | C4h 262144 | U2t 33554432
  unsigned short* Xff = (unsigned short*)d_ws;
  unsigned short* C4k = Xff + 33554432u;
  unsigned short* C2h = C4k + 1048576u;
  unsigned short* C4h = C2h + 262144u;
  unsigned short* U2t = C4h + 262144u;

  cvt_fold22<<<4096, 512, 0, stream>>>(x, Xff);  // one block per (b,v): 8*512
  gen_cos3<<<6144, 256, 0, stream>>>(C4k, C2h, C4h);
  // stage 1: odd k (K=1024) and even k (K=512, u+/u- classes)
  dct_gemm<0, 0><<<dim3(4, 64, 1), 512, 0, stream>>>(C4k, C4k, Xff, (void*)U2t);
  dct_gemm<0, 1><<<dim3(4, 64, 1), 512, 0, stream>>>(C2h, C4h, Xff, (void*)U2t);
  // stage 2: odd rows (K=1024) and even rows (K=512)
  dct_gemm<1, 0><<<dim3(8, 4, 8), 512, 0, stream>>>(C4k, C4k, U2t, (void*)out);
  dct_gemm<1, 1><<<dim3(8, 4, 8), 512, 0, stream>>>(C2h, C4h, U2t, (void*)out);
}

// Round 17
// 189.386 us; speedup vs baseline: 1.1899x; 1.0035x over previous
//
#include <hip/hip_runtime.h>
#include <hip/hip_bf16.h>
#include <hip/hip_fp16.h>

// 2D DCT-II via LEVEL-2 folded f16 MFMA GEMMs.  (R17 = R15 verbatim revert;
// R16's 8-phase port raced under graph replay — post-timing absmax 360.)
// Per 2048-DCT: k odd -> DCT4-1024 on w (K=1024); k=4s -> DCT2-512 on u+
// (K=512); k=4s+2 -> DCT4-512 on u- (K=512). MACs = 0.75x of level-1; both
// dims' 2-level folds fused into cvt_fold22 (f32 in, f16 out, LDS-bounce,
// conflict-free). GEMM: 256x256, 8 waves, BK=32, 4-buffer ring, counted
// vmcnt(4), XOR LDS swizzle (0 conflicts), setprio, bijective XCD chunk
// swizzle. Best measured: 190.06 us.

typedef _Float16 half8 __attribute__((ext_vector_type(8)));
typedef float f32x4 __attribute__((ext_vector_type(4)));
typedef unsigned int uint32;

constexpr int TILE_E = 256 * 32;  // 8192 f16 = 16KB

__device__ __forceinline__ unsigned short f2h_bits(float f) {
  _Float16 h = (_Float16)f;
  return __builtin_bit_cast(unsigned short, h);
}
__device__ __forceinline__ uint32 pk2(float a, float b) {
  return f2h_bits(a) | ((uint32)f2h_bits(b) << 16);
}

__device__ __forceinline__ void gload_lds16(const unsigned short* g, unsigned short* l) {
  __builtin_amdgcn_global_load_lds((const __attribute__((address_space(1))) void*)g,
                                   (__attribute__((address_space(3))) void*)l,
                                   16, 0, 0);
}

#define CFENCE asm volatile("" ::: "memory")

// Stored f16 index for logical (tile row r, 16B k-slot byte cb); stored rows
// are 128B (two logical rows); slot' = ((r&1)<<2 | cb>>4) ^ ((r>>1)&7).
// Measured 0 bank conflicts (R2-R15).
__device__ __forceinline__ int swz_idx(int r, int cbyte) {
  int b = (r >> 1) * 128 + ((((r & 1) << 6) | cbyte) ^ (((r >> 1) & 7) << 4));
  return b >> 1;
}

// Stage a 256x32 f16 tile from G (row-major, stride ld); LDS dest LINEAR,
// swizzle realized by inverse-permuting per-lane global source addresses.
__device__ __forceinline__ void stage_tile(const unsigned short* __restrict__ G,
                                           int rowbase, int k0, int ld,
                                           unsigned short* lds, int wave, int lane) {
#pragma unroll
  for (int c = 0; c < 2; ++c) {
    const int p = c * 64 + wave * 8 + (lane >> 3);   // stored 128B row
    const int v = (lane & 7) ^ ((lane >> 3) & 7);    // inverse slot swizzle
    const int r = 2 * p + (v >> 2);                  // logical tile row
    const int kslot = v & 3;
    const unsigned short* src = G + (size_t)(rowbase + r) * ld + (k0 + kslot * 8);
    unsigned short* dst = lds + (c * 64 + wave * 8) * 64;  // wave-uniform
    gload_lds16(src, dst);
  }
}

// ---- convert + FULL 2-level 2D fold, LDS-bounce, conflict-free --------------
__global__ __launch_bounds__(512) void cvt_fold22(const float* __restrict__ x,
                                                  unsigned short* __restrict__ Xff) {
  __shared__ float Y[4][2048];  // 32 KB
  const int blk = blockIdx.x;   // 4096 = b*512 + v
  const int b = blk >> 9;
  const int v = blk & 511;
  const int j = threadIdx.x;    // 0..511
  const float* base = x + (size_t)b * 4194304;
  const float* r0 = base + (size_t)v * 2048;
  const float* r1 = base + (size_t)(2047 - v) * 2048;
  const float* r2 = base + (size_t)(1023 - v) * 2048;
  const float* r3 = base + (size_t)(1024 + v) * 2048;

  // phase 1: one float4 col-chunk per thread per row (c = 4j)
  {
    const int c = 4 * j;
    float4 a = *(const float4*)(r0 + c);
    float4 bb = *(const float4*)(r1 + c);
    float4 cc = *(const float4*)(r2 + c);
    float4 dd = *(const float4*)(r3 + c);
    float4 sp, sm, d0, d1;
    sp.x = (a.x + bb.x) + (cc.x + dd.x); sm.x = (a.x + bb.x) - (cc.x + dd.x);
    sp.y = (a.y + bb.y) + (cc.y + dd.y); sm.y = (a.y + bb.y) - (cc.y + dd.y);
    sp.z = (a.z + bb.z) + (cc.z + dd.z); sm.z = (a.z + bb.z) - (cc.z + dd.z);
    sp.w = (a.w + bb.w) + (cc.w + dd.w); sm.w = (a.w + bb.w) - (cc.w + dd.w);
    d0.x = a.x - bb.x; d1.x = cc.x - dd.x;
    d0.y = a.y - bb.y; d1.y = cc.y - dd.y;
    d0.z = a.z - bb.z; d1.z = cc.z - dd.z;
    d0.w = a.w - bb.w; d1.w = cc.w - dd.w;
    *(float4*)&Y[0][c] = sp;
    *(float4*)&Y[1][c] = sm;
    *(float4*)&Y[2][c] = d0;
    *(float4*)&Y[3][c] = d1;
  }
  __syncthreads();

  // phase 2: thread j -> output cols [4j, 4j+4) for all 4 output rows
  unsigned short* orow[4] = {
      Xff + ((size_t)b * 2048 + v) * 2048,
      Xff + ((size_t)b * 2048 + 512 + v) * 2048,
      Xff + ((size_t)b * 2048 + 1024 + v) * 2048,
      Xff + ((size_t)b * 2048 + 2047 - v) * 2048};
  const int c0 = 4 * j;
  int pA, pD, pB, pC, rng;
  if (j < 128) { rng = 0; pA = 4 * j; pD = 2044 - 4 * j; pB = 1020 - 4 * j; pC = 1024 + 4 * j; }
  else if (j < 256) { rng = 1; pA = 4 * j - 512; pD = 2556 - 4 * j; pB = 1532 - 4 * j; pC = 512 + 4 * j; }
  else { rng = 2; pA = 4 * j - 1024; pD = 3068 - 4 * j; pB = 0; pC = 0; }

#pragma unroll
  for (int t = 0; t < 4; ++t) {
    float val[4];
    float4 av = *(const float4*)&Y[t][pA];
    float4 dv = *(const float4*)&Y[t][pD];
    const float* A = (const float*)&av;
    const float* Dq = (const float*)&dv;
    if (rng == 2) {
#pragma unroll
      for (int e = 0; e < 4; ++e) val[e] = A[e] - Dq[3 - e];
    } else {
      float4 bv = *(const float4*)&Y[t][pB];
      float4 cv = *(const float4*)&Y[t][pC];
      const float* Bq = (const float*)&bv;
      const float* Cq = (const float*)&cv;
#pragma unroll
      for (int e = 0; e < 4; ++e) {
        float P = A[e] + Dq[3 - e];
        float M = Bq[3 - e] + Cq[e];
        val[e] = rng == 0 ? P + M : P - M;
      }
    }
    *(uint2*)(orow[t] + c0) = make_uint2(pk2(val[0], val[1]), pk2(val[2], val[3]));
  }
}

// ---- cosine matrices: C4k 1024x1024 (DCT-IV), C2h 512x512, C4h 512x512 ------
__global__ __launch_bounds__(256) void gen_cos3(unsigned short* __restrict__ C4k,
                                                unsigned short* __restrict__ C2h,
                                                unsigned short* __restrict__ C4h) {
  int idx = blockIdx.x * 256 + threadIdx.x;  // 1572864
  const float s = 7.6699039394282061e-4f;    // pi/4096
  if (idx < 1048576) {
    int k = idx >> 10, n = idx & 1023;
    int t = ((2 * n + 1) * (2 * k + 1)) & 8191;   // cos(pi(2n+1)(2k+1)/4096)
    C4k[idx] = f2h_bits(cosf((float)t * s));
  } else if (idx < 1310720) {
    int i2 = idx - 1048576;
    int k = i2 >> 9, n = i2 & 511;
    int t = ((2 * n + 1) * 4 * k) & 8191;         // cos(pi(2n+1)k/1024)
    C2h[i2] = f2h_bits(cosf((float)t * s));
  } else {
    int i2 = idx - 1310720;
    int k = i2 >> 9, n = i2 & 511;
    int t = ((2 * n + 1) * (4 * k + 2)) & 8191;   // cos(pi(2n+1)(2k+1)/2048)
    C4h[i2] = f2h_bits(cosf((float)t * s));
  }
}

// ---- pipelined GEMM (R11 structure) + bijective XCD chunk swizzle -----------
// MODE 0 (stage 1, f16 transposed out U2t[b][ktrue][m2]):
//   SPLIT 0: A cols [1024,2048)=w, B=M0=C4k,  K=1024, ktrue=2c+1
//   SPLIT 1: cls=bn>>1: A cols cls*512 (u+/u-), B=C2h/C4h, K=512, ktrue=4c+2cls
// MODE 1 (stage 2, fp32 out):
//   SPLIT 0: A=C4k (M=1024), B=U2t[z] cols [1024,2048), K=1024, rtrue=2p+1
//   SPLIT 1: cls=by>>1: A=C2h/C4h, B=U2t[z] cols cls*512, K=512, rtrue=4p+2cls
template <int MODE, int SPLIT>
__global__ __launch_bounds__(512) void dct_gemm(
    const unsigned short* __restrict__ M0, const unsigned short* __restrict__ M1,
    const unsigned short* __restrict__ D, void* __restrict__ outp) {
  constexpr int K = SPLIT ? 512 : 1024;
  constexpr int NT = K / 32;
  __shared__ unsigned short As[4 * TILE_E];
  __shared__ unsigned short Bs[4 * TILE_E];

  const int tid = threadIdx.x;
  const int lane = tid & 63;
  const int wave = tid >> 6;
  const int wr = wave >> 2;
  const int wc = wave & 3;

  // XCD-chunked bijective remap (nwg = 256 for all instantiations)
  int lin, f, bmx, bnx, z;
  if (MODE == 0) {
    lin = blockIdx.y * 4 + blockIdx.x;            // gx=4, gy=64
    f = (lin & 7) * 32 + (lin >> 3);
    bnx = f & 3;
    bmx = f >> 2;
    z = 0;
  } else {
    lin = (blockIdx.z * 4 + blockIdx.y) * 8 + blockIdx.x;  // gx=8, gy=4, gz=8
    f = (lin & 7) * 32 + (lin >> 3);
    bnx = f & 7;
    bmx = (f >> 3) & 3;
    z = f >> 5;
  }

  const unsigned short* Ag;
  const unsigned short* Bg;
  int lda, ldb, arow, brow, cls;
  if (MODE == 0) {
    cls = SPLIT ? (bnx >> 1) : 0;
    Ag = D + (SPLIT ? cls * 512 : 1024);
    lda = 2048;
    arow = bmx * 256;
    Bg = SPLIT ? (cls ? M1 : M0) : M0;
    ldb = K;
    brow = (SPLIT ? (bnx & 1) : bnx) * 256;
  } else {
    cls = SPLIT ? (bmx >> 1) : 0;
    Ag = SPLIT ? (cls ? M1 : M0) : M0;
    lda = K;
    arow = (SPLIT ? (bmx & 1) : bmx) * 256;
    Bg = D + (size_t)z * 4194304u + (SPLIT ? cls * 512 : 1024);
    ldb = 2048;
    brow = bnx * 256;
  }

  const int frc = lane & 15;
  const int cb = (lane >> 4) << 4;

  f32x4 acc[8][4] = {};

  stage_tile(Ag, arow, 0, lda, &As[0], wave, lane);
  stage_tile(Bg, brow, 0, ldb, &Bs[0], wave, lane);
  stage_tile(Ag, arow, 32, lda, &As[TILE_E], wave, lane);
  stage_tile(Bg, brow, 32, ldb, &Bs[TILE_E], wave, lane);
  asm volatile("s_waitcnt vmcnt(4)" ::: "memory");
  CFENCE; __builtin_amdgcn_s_barrier(); CFENCE;

  for (int t = 0; t < NT; ++t) {
    const unsigned short* at = &As[(t & 3) * TILE_E];
    const unsigned short* bt = &Bs[(t & 3) * TILE_E];
    half8 af[4], bf[4];

    // phase 1: reads (quadrant mh=0) + stage A(t+2)
#pragma unroll
    for (int m = 0; m < 4; ++m)
      af[m] = *(const half8*)&at[swz_idx(wr * 128 + m * 16 + frc, cb)];
#pragma unroll
    for (int n = 0; n < 4; ++n)
      bf[n] = *(const half8*)&bt[swz_idx(wc * 64 + n * 16 + frc, cb)];
    if (t + 2 < NT)
      stage_tile(Ag, arow, (t + 2) * 32, lda, &As[((t + 2) & 3) * TILE_E], wave, lane);
    CFENCE; __builtin_amdgcn_s_barrier(); CFENCE;
    __builtin_amdgcn_s_setprio(1);
#pragma unroll
    for (int m = 0; m < 4; ++m)
#pragma unroll
      for (int n = 0; n < 4; ++n)
        acc[m][n] = __builtin_amdgcn_mfma_f32_16x16x32_f16(af[m], bf[n], acc[m][n], 0, 0, 0);
    __builtin_amdgcn_s_setprio(0);

    // phase 2: reads (quadrant mh=1) + stage B(t+2) + counted boundary
#pragma unroll
    for (int m = 0; m < 4; ++m)
      af[m] = *(const half8*)&at[swz_idx(wr * 128 + 64 + m * 16 + frc, cb)];
    if (t + 2 < NT)
      stage_tile(Bg, brow, (t + 2) * 32, ldb, &Bs[((t + 2) & 3) * TILE_E], wave, lane);
    if (t < NT - 2)
      asm volatile("s_waitcnt vmcnt(4)" ::: "memory");
    else if (t == NT - 2)
      asm volatile("s_waitcnt vmcnt(0)" ::: "memory");
    CFENCE; __builtin_amdgcn_s_barrier(); CFENCE;
    __builtin_amdgcn_s_setprio(1);
#pragma unroll
    for (int m = 0; m < 4; ++m)
#pragma unroll
      for (int n = 0; n < 4; ++n)
        acc[m + 4][n] =
            __builtin_amdgcn_mfma_f32_16x16x32_f16(af[m], bf[n], acc[m + 4][n], 0, 0, 0);
    __builtin_amdgcn_s_setprio(0);
  }

  // epilogue; D mapping: col = lane&15, row = (lane>>4)*4 + i
  if (MODE == 0) {
    unsigned short* U2t = (unsigned short*)outp;
#pragma unroll
    for (int mi = 0; mi < 8; ++mi) {
      const int r = arow + wr * 128 + (mi >> 2) * 64 + (mi & 3) * 16 + (lane >> 4) * 4;
      const int b = r >> 11;
      const int rb = r & 2047;
#pragma unroll
      for (int n = 0; n < 4; ++n) {
        const int ccls = brow + wc * 64 + n * 16 + frc;
        const int ktrue = SPLIT ? (4 * ccls + 2 * cls) : (2 * ccls + 1);
        uint32 lo = f2h_bits(acc[mi][n][0]) | ((uint32)f2h_bits(acc[mi][n][1]) << 16);
        uint32 hi = f2h_bits(acc[mi][n][2]) | ((uint32)f2h_bits(acc[mi][n][3]) << 16);
        *(uint2*)&U2t[(size_t)b * 4194304 + (size_t)ktrue * 2048 + rb] =
            make_uint2(lo, hi);
      }
    }
  } else {
    float* out = (float*)outp + (size_t)z * 4194304;
#pragma unroll
    for (int mi = 0; mi < 8; ++mi) {
      const int p0 = arow + wr * 128 + (mi >> 2) * 64 + (mi & 3) * 16 + (lane >> 4) * 4;
#pragma unroll
      for (int n = 0; n < 4; ++n) {
        const int cg = brow + wc * 64 + n * 16 + frc;
#pragma unroll
        for (int i = 0; i < 4; ++i) {
          const int rtrue = SPLIT ? (4 * (p0 + i) + 2 * cls) : (2 * (p0 + i) + 1);
          out[(size_t)rtrue * 2048 + cg] = acc[mi][n][i];
        }
      }
    }
  }
}

extern "C" void kernel_launch(void* const* d_in, const int* in_sizes, int n_in,
                              void* d_out, int out_size, void* d_ws,
                              size_t ws_size, hipStream_t stream) {
  const float* x = (const float*)d_in[0];
  float* out = (float*)d_out;

  // workspace (f16 elems):
  // Xff 33554432 | C4k 1048576 | C2h 262144 | C4h 262144 | U2t 33554432
  unsigned short* Xff = (unsigned short*)d_ws;
  unsigned short* C4k = Xff + 33554432u;
  unsigned short* C2h = C4k + 1048576u;
  unsigned short* C4h = C2h + 262144u;
  unsigned short* U2t = C4h + 262144u;

  cvt_fold22<<<4096, 512, 0, stream>>>(x, Xff);  // one block per (b,v): 8*512
  gen_cos3<<<6144, 256, 0, stream>>>(C4k, C2h, C4h);
  // stage 1: odd k (K=1024) and even k (K=512, u+/u- classes)
  dct_gemm<0, 0><<<dim3(4, 64, 1), 512, 0, stream>>>(C4k, C4k, Xff, (void*)U2t);
  dct_gemm<0, 1><<<dim3(4, 64, 1), 512, 0, stream>>>(C2h, C4h, Xff, (void*)U2t);
  // stage 2: odd rows (K=1024) and even rows (K=512)
  dct_gemm<1, 0><<<dim3(8, 4, 8), 512, 0, stream>>>(C4k, C4k, U2t, (void*)out);
  dct_gemm<1, 1><<<dim3(8, 4, 8), 512, 0, stream>>>(C2h, C4h, U2t, (void*)out);
}